// Round 5
// baseline (5256.972 us; speedup 1.0000x reference)
//
#include <hip/hip_runtime.h>
#include <cstdint>
#include <cstddef>

typedef unsigned short u16;
typedef unsigned int u32;
typedef float f32x4 __attribute__((ext_vector_type(4)));
typedef _Float16 f16x8 __attribute__((ext_vector_type(8)));

__device__ __forceinline__ u16 f2h(float x) {
  _Float16 h = (_Float16)x;
  return __builtin_bit_cast(u16, h);
}
__device__ __forceinline__ float sigm(float x) { return 1.f / (1.f + __expf(-x)); }

__device__ __forceinline__ void gll16(const void* g, void* l) {
  __builtin_amdgcn_global_load_lds(
      (const __attribute__((address_space(1))) void*)g,
      (__attribute__((address_space(3))) void*)l, 16, 0, 0);
}

enum { M_PLAIN = 0, M_TANH = 1, M_OUT = 2 };

struct GemmP {
  const u16* A; int lda;   // fp16 activations [1024, lda]
  const u16* W; int ldw;   // fp16 weights, row-major [N or 4H, ldw]
  int K;                   // multiple of 64
  const float* bias;
  int mode;                // non-CELL epilogue select
  int czero;               // CELL: treat c_prev as 0 (skip read)
  u16* d0; int ld0;        // fp16 dest (pre-offset)
  u16* d1; int ld1;        // optional second fp16 dest
  float* c0;               // CELL: c-state; M_TANH: f32 dest
  float* c1;               // M_TANH: second f32 dest
  float* fout;             // M_OUT: d_out + step*90
};

// C = A @ W^T (+bias), fused epilogue. 512 threads = 8 waves (4 row x 2 col),
// block tile 128x128. Triple-buffered LDS + raw s_barrier + counted vmcnt:
// 2 tiles prefetched ahead, never drain vmcnt to 0 in steady state.
// CELL=true: 128 rows x 32 cols x 4 gates; i/f/g/o land in the same lane ->
// LSTM pointwise fused in epilogue.
template <bool CELL>
__global__ __launch_bounds__(512, 2) void gk(GemmP p) {
  __shared__ __align__(16) char sm[98304];  // 3 x (16K A-tile + 16K W-tile)
  const int tid = threadIdx.x;
  const int lane = tid & 63, wid = tid >> 6;
  const int wr = wid >> 1, wc = wid & 1;
  const int bRow = blockIdx.x * 128;
  const int nBase = blockIdx.y * (CELL ? 32 : 128);
  const int col0 = lane & 15, g4 = lane >> 4;

  f32x4 acc[2][4];
#pragma unroll
  for (int m = 0; m < 2; ++m)
#pragma unroll
    for (int n = 0; n < 4; ++n) acc[m][n] = f32x4{0.f, 0.f, 0.f, 0.f};

  const char* Ab = (const char*)p.A;
  const char* Wb = (const char*)p.W;
  const size_t ldaB = (size_t)p.lda * 2, ldwB = (size_t)p.ldw * 2;

  // Stage 128x64 A-tile + 128x64 W-tile into buffer `buf`. LDS dest linear
  // (global_load_lds constraint); XOR 16B-chunk swizzle applied on the GLOBAL
  // source address, undone identically on the ds_read side (involution).
  auto stage = [&](int buf, int kt) {
    char* base = sm + buf * 32768;
    const int kb = kt * 128;  // byte offset along K
#pragma unroll
    for (int i = 0; i < 2; ++i) {
      const int s = i * 512 + tid;
      const int row = s >> 3, ch = s & 7;
      const int sch = ch ^ (row & 7);
      gll16(Ab + (size_t)(bRow + row) * ldaB + (size_t)(kb + sch * 16),
            base + s * 16);
      const int wrow = CELL ? ((row >> 5) * 1024 + nBase + (row & 31)) : (nBase + row);
      gll16(Wb + (size_t)wrow * ldwB + (size_t)(kb + sch * 16),
            base + 16384 + s * 16);
    }
  };

  const int nt = p.K >> 6;
  stage(0, 0);
  stage(1, 1);
  int sb = 2, cb = 0;
  for (int t = 0; t < nt; ++t) {
    if (t + 2 < nt) {
      stage(sb, t + 2);
      sb = (sb == 2) ? 0 : sb + 1;
    }
    const int ahead = (nt - 1 - t < 2) ? (nt - 1 - t) : 2;
    // wait only for tile t's 4 loads/thread; keep ahead*4 in flight
    if (ahead == 2)      asm volatile("s_waitcnt vmcnt(8)" ::: "memory");
    else if (ahead == 1) asm volatile("s_waitcnt vmcnt(4)" ::: "memory");
    else                 asm volatile("s_waitcnt vmcnt(0)" ::: "memory");
    __builtin_amdgcn_s_barrier();

    const char* Abase = sm + cb * 32768;
    const char* Wbase = Abase + 16384;
    f16x8 af[2][2], wf[2][4];
#pragma unroll
    for (int kf = 0; kf < 2; ++kf) {
      const int ch = kf * 4 + g4;
#pragma unroll
      for (int m = 0; m < 2; ++m) {
        const int r = wr * 32 + m * 16 + col0;
        af[kf][m] = *(const f16x8*)(Abase + r * 128 + ((ch ^ (r & 7)) << 4));
      }
#pragma unroll
      for (int n = 0; n < 4; ++n) {
        const int r = CELL ? (n * 32 + wc * 16 + col0) : (wc * 64 + n * 16 + col0);
        wf[kf][n] = *(const f16x8*)(Wbase + r * 128 + ((ch ^ (r & 7)) << 4));
      }
    }
#pragma unroll
    for (int kf = 0; kf < 2; ++kf)
#pragma unroll
      for (int m = 0; m < 2; ++m)
#pragma unroll
        for (int n = 0; n < 4; ++n)
          acc[m][n] = __builtin_amdgcn_mfma_f32_16x16x32_f16(af[kf][m], wf[kf][n],
                                                             acc[m][n], 0, 0, 0);
    // all LDS reads of buf[cb] done before any wave re-stages into it
    asm volatile("s_waitcnt lgkmcnt(0)" ::: "memory");
    __builtin_amdgcn_s_barrier();
    cb = (cb == 2) ? 0 : cb + 1;
  }

  if (CELL) {
    const int j = nBase + wc * 16 + col0;
    const float bi = p.bias[j], bf_ = p.bias[j + 1024];
    const float bg = p.bias[j + 2048], bo = p.bias[j + 3072];
#pragma unroll
    for (int m = 0; m < 2; ++m) {
#pragma unroll
      for (int r = 0; r < 4; ++r) {
        const int b = bRow + wr * 32 + m * 16 + g4 * 4 + r;
        const float gi = acc[m][0][r] + bi;
        const float gf = acc[m][1][r] + bf_;
        const float gg = acc[m][2][r] + bg;
        const float go = acc[m][3][r] + bo;
        const size_t ci = (size_t)b * 1024 + j;
        const float cprev = p.czero ? 0.f : p.c0[ci];
        const float cn = sigm(gf) * cprev + sigm(gi) * tanhf(gg);
        p.c0[ci] = cn;
        const u16 hv = f2h(sigm(go) * tanhf(cn));
        p.d0[(size_t)b * p.ld0 + j] = hv;
        if (p.d1) p.d1[(size_t)b * p.ld1 + j] = hv;
      }
    }
  } else {
#pragma unroll
    for (int m = 0; m < 2; ++m)
#pragma unroll
      for (int n = 0; n < 4; ++n)
#pragma unroll
        for (int r = 0; r < 4; ++r) {
          const int b = bRow + wr * 32 + m * 16 + g4 * 4 + r;
          const int j = nBase + wc * 64 + n * 16 + col0;
          float v = acc[m][n][r] + p.bias[j];
          if (p.mode == M_TANH) {
            v = tanhf(v);
            const u16 hv = f2h(v);
            p.d0[(size_t)b * p.ld0 + j] = hv;
            if (p.d1) p.d1[(size_t)b * p.ld1 + j] = hv;
            if (p.c0) p.c0[(size_t)b * 1024 + j] = v;
            if (p.c1) p.c1[(size_t)b * 1024 + j] = v;
          } else if (p.mode == M_PLAIN) {
            p.d0[(size_t)b * p.ld0 + j] = f2h(v);
          } else {  // M_OUT
            if (j < 90) {
              p.d0[(size_t)b * p.ld0 + j] = f2h(v);
              p.fout[(size_t)b * 5760 + j] = sigm(v);
            }
          }
        }
  }
}

// ---- prologue kernels ----

// dst[r, 0:Ka]=a[r]; dst[r, Ka:Ka+gap]=0; dst[r, Ka+gap:+Kb]=b[r]; rows>=srcRows -> 0
__global__ void pack_w(u16* dst, const float* a, int Ka, const float* b, int Kb,
                       int gap, int Kp, int srcRows) {
  const int r = blockIdx.y;
  const int c = blockIdx.x * 256 + threadIdx.x;
  if (c >= Kp) return;
  float v = 0.f;
  if (r < srcRows) {
    if (c < Ka) v = a[(size_t)r * Ka + c];
    else if (c >= Ka + gap && c < Ka + gap + Kb) v = b[(size_t)r * Kb + (c - Ka - gap)];
  }
  dst[(size_t)r * Kp + c] = f2h(v);
}

struct BiasAll {
  float *bz, *bc0, *bc1, *bfc1, *bcfc, *bb0, *bb1, *bout;
  const float *fzb, *ci0, *ch0, *ci1, *ch1, *f1b, *cfb, *bi0, *bh0, *bi1, *bh1, *ob;
};
__global__ void pack_biases(BiasAll q) {
  int i = blockIdx.x * 256 + threadIdx.x;
  if (i < 1024) { q.bz[i] = q.fzb[i]; return; } i -= 1024;
  if (i < 4096) { q.bc0[i] = q.ci0[i] + q.ch0[i]; return; } i -= 4096;
  if (i < 4096) { q.bc1[i] = q.ci1[i] + q.ch1[i]; return; } i -= 4096;
  if (i < 512)  { q.bfc1[i] = q.f1b[i]; return; } i -= 512;
  if (i < 512)  { q.bcfc[i] = q.cfb[i]; return; } i -= 512;
  if (i < 4096) { q.bb0[i] = q.bi0[i] + q.bh0[i]; return; } i -= 4096;
  if (i < 4096) { q.bb1[i] = q.bi1[i] + q.bh1[i]; return; } i -= 4096;
  if (i < 128)  { q.bout[i] = (i < 90) ? q.ob[i] : 0.f; }
}

__global__ void conv_h(u16* dst, const float* src, long n) {
  for (long i = (long)blockIdx.x * blockDim.x + threadIdx.x; i < n;
       i += (long)gridDim.x * blockDim.x)
    dst[i] = f2h(src[i]);
}

// zero Xc0 cols 0:512 (cond_in0) and Xb0 cols 512:640 (p slot + 38-col pad).
// The pad cols (602:640) are never written again -> stay zero all call.
__global__ void zero_init(u32* xc0, u32* xb0) {
  const int i = blockIdx.x * 256 + threadIdx.x;
  if (i < 1024 * 256) {
    xc0[(i >> 8) * 768 + (i & 255)] = 0;
  } else {
    const int k = i - 1024 * 256;  // k < 1024*64
    xb0[(k >> 6) * 832 + 256 + (k & 63)] = 0;
  }
}

extern "C" void kernel_launch(void* const* d_in, const int* in_sizes, int n_in,
                              void* d_out, int out_size, void* d_ws, size_t ws_size,
                              hipStream_t stream) {
  const float* z      = (const float*)d_in[0];
  const float* fc_z_w = (const float*)d_in[2];
  const float* fc_z_b = (const float*)d_in[3];
  const float* cWih0  = (const float*)d_in[4];
  const float* cWhh0  = (const float*)d_in[5];
  const float* cbih0  = (const float*)d_in[6];
  const float* cbhh0  = (const float*)d_in[7];
  const float* cWih1  = (const float*)d_in[8];
  const float* cWhh1  = (const float*)d_in[9];
  const float* cbih1  = (const float*)d_in[10];
  const float* cbhh1  = (const float*)d_in[11];
  const float* fc1_w  = (const float*)d_in[12];
  const float* fc1_b  = (const float*)d_in[13];
  const float* cfc_w  = (const float*)d_in[14];
  const float* cfc_b  = (const float*)d_in[15];
  const float* bWih0  = (const float*)d_in[16];
  const float* bWhh0  = (const float*)d_in[17];
  const float* bbih0  = (const float*)d_in[18];
  const float* bbhh0  = (const float*)d_in[19];
  const float* bWih1  = (const float*)d_in[20];
  const float* bWhh1  = (const float*)d_in[21];
  const float* bbih1  = (const float*)d_in[22];
  const float* bbhh1  = (const float*)d_in[23];
  const float* out_w  = (const float*)d_in[24];
  const float* out_b  = (const float*)d_in[25];
  float* outp = (float*)d_out;

  char* w = (char*)d_ws;
  auto alloc = [&](size_t bytes) {
    char* p = w;
    w += (bytes + 255) & ~(size_t)255;
    return p;
  };
  u16* Wz   = (u16*)alloc((size_t)1024 * 512 * 2);
  u16* Wc0  = (u16*)alloc((size_t)4096 * 1536 * 2);
  u16* Wc1  = (u16*)alloc((size_t)4096 * 2048 * 2);
  u16* Wb0  = (u16*)alloc((size_t)4096 * 1664 * 2);
  u16* Wb1  = (u16*)alloc((size_t)4096 * 2048 * 2);
  u16* Wfc1 = (u16*)alloc((size_t)512 * 1024 * 2);
  u16* Wcfc = (u16*)alloc((size_t)512 * 512 * 2);
  u16* Wout = (u16*)alloc((size_t)128 * 1024 * 2);
  u16* zh   = (u16*)alloc((size_t)1024 * 512 * 2);
  u16* Xc0  = (u16*)alloc((size_t)1024 * 1536 * 2);  // [cond_in 512 | h1 1024]
  u16* Xc1  = (u16*)alloc((size_t)1024 * 2048 * 2);  // [h1 1024 | h2 1024]
  u16* Xb0  = (u16*)alloc((size_t)1024 * 1664 * 2);  // [emb 512|p 90|pad 38|bh1 1024]
  u16* Xb1  = (u16*)alloc((size_t)1024 * 2048 * 2);  // [bh1 1024 | bh2 1024]
  float* cc0  = (float*)alloc((size_t)1024 * 1024 * 4);
  float* cc1  = (float*)alloc((size_t)1024 * 1024 * 4);
  float* cbb0 = (float*)alloc((size_t)1024 * 1024 * 4);
  float* cbb1 = (float*)alloc((size_t)1024 * 1024 * 4);
  float* bz   = (float*)alloc(1024 * 4);
  float* bc0  = (float*)alloc(4096 * 4);
  float* bc1  = (float*)alloc(4096 * 4);
  float* bfc1 = (float*)alloc(512 * 4);
  float* bcfc = (float*)alloc(512 * 4);
  float* bb0  = (float*)alloc(4096 * 4);
  float* bb1  = (float*)alloc(4096 * 4);
  float* bout = (float*)alloc(128 * 4);

  const dim3 blk(256), blk5(512);

  // --- prologue: pack weights (fp16, div-free 2D), biases, init state ---
  pack_w<<<dim3(2, 1024), blk, 0, stream>>>(Wz,   fc_z_w, 512,  nullptr, 0,    0,  512,  1024);
  pack_w<<<dim3(6, 4096), blk, 0, stream>>>(Wc0,  cWih0,  512,  cWhh0,   1024, 0,  1536, 4096);
  pack_w<<<dim3(8, 4096), blk, 0, stream>>>(Wc1,  cWih1,  1024, cWhh1,   1024, 0,  2048, 4096);
  pack_w<<<dim3(7, 4096), blk, 0, stream>>>(Wb0,  bWih0,  602,  bWhh0,   1024, 38, 1664, 4096);
  pack_w<<<dim3(8, 4096), blk, 0, stream>>>(Wb1,  bWih1,  1024, bWhh1,   1024, 0,  2048, 4096);
  pack_w<<<dim3(4, 512),  blk, 0, stream>>>(Wfc1, fc1_w,  1024, nullptr, 0,    0,  1024, 512);
  pack_w<<<dim3(2, 512),  blk, 0, stream>>>(Wcfc, cfc_w,  512,  nullptr, 0,    0,  512,  512);
  pack_w<<<dim3(4, 128),  blk, 0, stream>>>(Wout, out_w,  1024, nullptr, 0,    0,  1024, 90);
  {
    BiasAll q{bz, bc0, bc1, bfc1, bcfc, bb0, bb1, bout,
              fc_z_b, cbih0, cbhh0, cbih1, cbhh1, fc1_b, cfc_b,
              bbih0, bbhh0, bbih1, bbhh1, out_b};
    pack_biases<<<dim3(80), blk, 0, stream>>>(q);
  }
  conv_h<<<dim3(512), blk, 0, stream>>>(zh, z, 1024L * 512);
  zero_init<<<dim3(1280), blk, 0, stream>>>((u32*)Xc0, (u32*)Xb0);

  // s0 = tanh(z @ Wz^T + bz) -> h1, h2 (fp16) and c1, c2 (f32)
  {
    GemmP p;
    p.A = zh; p.lda = 512; p.W = Wz; p.ldw = 512; p.K = 512; p.bias = bz;
    p.mode = M_TANH; p.czero = 0;
    p.d0 = Xc0 + 512; p.ld0 = 1536; p.d1 = Xc1 + 1024; p.ld1 = 2048;
    p.c0 = cc0; p.c1 = cc1; p.fout = nullptr;
    gk<false><<<dim3(8, 8), blk5, 0, stream>>>(p);
  }

  for (int t = 0; t < 16; ++t) {
    {  // conductor layer 0
      GemmP p;
      p.A = Xc0; p.lda = 1536; p.W = Wc0; p.ldw = 1536; p.K = 1536; p.bias = bc0;
      p.mode = 0; p.czero = 0;
      p.d0 = Xc0 + 512; p.ld0 = 1536; p.d1 = Xc1; p.ld1 = 2048;
      p.c0 = cc0; p.c1 = nullptr; p.fout = nullptr;
      gk<true><<<dim3(8, 32), blk5, 0, stream>>>(p);
    }
    {  // conductor layer 1
      GemmP p;
      p.A = Xc1; p.lda = 2048; p.W = Wc1; p.ldw = 2048; p.K = 2048; p.bias = bc1;
      p.mode = 0; p.czero = 0;
      p.d0 = Xc1 + 1024; p.ld0 = 2048; p.d1 = nullptr; p.ld1 = 0;
      p.c0 = cc1; p.c1 = nullptr; p.fout = nullptr;
      gk<true><<<dim3(8, 32), blk5, 0, stream>>>(p);
    }
    {  // cond_out = h2 @ fc1^T + b -> Xc0 cols 0:512
      GemmP p;
      p.A = Xc1 + 1024; p.lda = 2048; p.W = Wfc1; p.ldw = 1024; p.K = 1024;
      p.bias = bfc1; p.mode = M_PLAIN; p.czero = 0;
      p.d0 = Xc0; p.ld0 = 1536; p.d1 = nullptr; p.ld1 = 0;
      p.c0 = nullptr; p.c1 = nullptr; p.fout = nullptr;
      gk<false><<<dim3(8, 4), blk5, 0, stream>>>(p);
    }
    {  // emb = tanh(cond_out @ cfc^T + b) -> Xb0 cols 0:512
      GemmP p;
      p.A = Xc0; p.lda = 1536; p.W = Wcfc; p.ldw = 512; p.K = 512;
      p.bias = bcfc; p.mode = M_TANH; p.czero = 0;
      p.d0 = Xb0; p.ld0 = 1664; p.d1 = nullptr; p.ld1 = 0;
      p.c0 = nullptr; p.c1 = nullptr; p.fout = nullptr;
      gk<false><<<dim3(8, 4), blk5, 0, stream>>>(p);
    }
    for (int s = 0; s < 4; ++s) {
      {  // bottom layer 0; s==0: bh1=0 & c=0 -> K=640, czero (skips zeroing pass)
        GemmP p;
        p.A = Xb0; p.lda = 1664; p.W = Wb0; p.ldw = 1664;
        p.K = (s == 0) ? 640 : 1664; p.bias = bb0;
        p.mode = 0; p.czero = (s == 0);
        p.d0 = Xb0 + 640; p.ld0 = 1664; p.d1 = Xb1; p.ld1 = 2048;
        p.c0 = cbb0; p.c1 = nullptr; p.fout = nullptr;
        gk<true><<<dim3(8, 32), blk5, 0, stream>>>(p);
      }
      {  // bottom layer 1; s==0: bh2=0 & c=0 -> K=1024, czero
        GemmP p;
        p.A = Xb1; p.lda = 2048; p.W = Wb1; p.ldw = 2048;
        p.K = (s == 0) ? 1024 : 2048; p.bias = bb1;
        p.mode = 0; p.czero = (s == 0);
        p.d0 = Xb1 + 1024; p.ld0 = 2048; p.d1 = nullptr; p.ld1 = 0;
        p.c0 = cbb1; p.c1 = nullptr; p.fout = nullptr;
        gk<true><<<dim3(8, 32), blk5, 0, stream>>>(p);
      }
      {  // p = bh2 @ out_w^T + b ; p (fp16) -> Xb0 p-slot, sigmoid -> d_out
        GemmP p;
        p.A = Xb1 + 1024; p.lda = 2048; p.W = Wout; p.ldw = 1024; p.K = 1024;
        p.bias = bout; p.mode = M_OUT; p.czero = 0;
        p.d0 = Xb0 + 512; p.ld0 = 1664; p.d1 = nullptr; p.ld1 = 0;
        p.c0 = nullptr; p.c1 = nullptr;
        p.fout = outp + (size_t)(t * 4 + s) * 90;
        gk<false><<<dim3(8, 1), blk5, 0, stream>>>(p);
      }
    }
  }
}

// Round 6
// 5003.216 us; speedup vs baseline: 1.0507x; 1.0507x over previous
//
#include <hip/hip_runtime.h>
#include <cstdint>
#include <cstddef>

typedef unsigned short u16;
typedef unsigned int u32;
typedef float f32x4 __attribute__((ext_vector_type(4)));
typedef _Float16 f16x8 __attribute__((ext_vector_type(8)));

__device__ __forceinline__ u16 f2h(float x) {
  _Float16 h = (_Float16)x;
  return __builtin_bit_cast(u16, h);
}
__device__ __forceinline__ float sigm(float x) { return 1.f / (1.f + __expf(-x)); }

__device__ __forceinline__ void gll16(const void* g, void* l) {
  __builtin_amdgcn_global_load_lds(
      (const __attribute__((address_space(1))) void*)g,
      (__attribute__((address_space(3))) void*)l, 16, 0, 0);
}

enum { M_PLAIN = 0, M_TANH = 1, M_OUT = 2 };

struct GemmP {
  const u16* A; int lda;   // fp16 activations [1024, lda]
  const u16* W; int ldw;   // fp16 weights, row-major [N or 4H, ldw]
  int K;                   // multiple of 64
  const float* bias;
  int mode;                // non-CELL epilogue select
  int czero;               // CELL: treat c_prev as 0 (skip read)
  u16* d0; int ld0;        // fp16 dest (pre-offset)
  u16* d1; int ld1;        // optional second fp16 dest
  float* c0;               // CELL: c-state; M_TANH: f32 dest
  float* c1;               // M_TANH: second f32 dest
  float* fout;             // M_OUT: d_out + step*90
};

// C = A @ W^T (+bias), fused epilogue. 512 threads = 8 waves (4 row x 2 col),
// block tile 128x128. FOUR LDS buffers, prefetch depth 2, ONE s_barrier per
// K-step (second barrier provably redundant at depth 2 with 4 buffers:
// stage target (t+2)&3 was last read at t-2, whose ds_reads completed before
// that wave's t-2 MFMAs issued; barrier-per-iter bounds skew to <1 iter).
// CELL=true: 1-D grid 256, XCD-swizzled so each XCD owns 4 whole weight
// panels (panel read by 8 row-blocks stays in one L2). i/f/g/o per (b,j)
// land in one lane -> LSTM pointwise fused in epilogue.
template <bool CELL>
__global__ __launch_bounds__(512, 2) void gk(GemmP p) {
  __shared__ __align__(16) char sm[131072];  // 4 x (16K A-tile + 16K W-tile)
  const int tid = threadIdx.x;
  const int lane = tid & 63, wid = tid >> 6;
  const int wr = wid >> 1, wc = wid & 1;
  int bx, by;
  if (CELL) {
    // hw%8 = XCD (round-robin dispatch). Each XCD: 4 weight panels x 8 row-blocks.
    const int hw = blockIdx.x;
    const int xcd = hw & 7, idx = hw >> 3;
    by = xcd * 4 + (idx >> 3);  // weight panel [0,32)
    bx = idx & 7;               // row block [0,8)
  } else {
    bx = blockIdx.x;
    by = blockIdx.y;
  }
  const int bRow = bx * 128;
  const int nBase = by * (CELL ? 32 : 128);
  const int col0 = lane & 15, g4 = lane >> 4;

  f32x4 acc[2][4];
#pragma unroll
  for (int m = 0; m < 2; ++m)
#pragma unroll
    for (int n = 0; n < 4; ++n) acc[m][n] = f32x4{0.f, 0.f, 0.f, 0.f};

  const char* Ab = (const char*)p.A;
  const char* Wb = (const char*)p.W;
  const size_t ldaB = (size_t)p.lda * 2, ldwB = (size_t)p.ldw * 2;

  // Stage 128x64 A-tile + 128x64 W-tile into buffer `buf`. LDS dest linear
  // (global_load_lds constraint); XOR 16B-chunk swizzle applied on the GLOBAL
  // source address, undone identically on the ds_read side (involution).
  auto stage = [&](int buf, int kt) {
    char* base = sm + buf * 32768;
    const int kb = kt * 128;  // byte offset along K
#pragma unroll
    for (int i = 0; i < 2; ++i) {
      const int s = i * 512 + tid;
      const int row = s >> 3, ch = s & 7;
      const int sch = ch ^ (row & 7);
      gll16(Ab + (size_t)(bRow + row) * ldaB + (size_t)(kb + sch * 16),
            base + s * 16);
      const int wrow = CELL ? ((row >> 5) * 1024 + nBase + (row & 31)) : (nBase + row);
      gll16(Wb + (size_t)wrow * ldwB + (size_t)(kb + sch * 16),
            base + 16384 + s * 16);
    }
  };

  const int nt = p.K >> 6;
  stage(0, 0);
  stage(1, 1);
  for (int t = 0; t < nt; ++t) {
    if (t + 2 < nt) stage((t + 2) & 3, t + 2);
    const int ahead = (nt - 1 - t < 2) ? (nt - 1 - t) : 2;
    // wait only for tile t's 4 loads/thread; keep ahead*4 in flight
    if (ahead == 2)      asm volatile("s_waitcnt vmcnt(8)" ::: "memory");
    else if (ahead == 1) asm volatile("s_waitcnt vmcnt(4)" ::: "memory");
    else                 asm volatile("s_waitcnt vmcnt(0)" ::: "memory");
    __builtin_amdgcn_s_barrier();

    const char* Abase = sm + (t & 3) * 32768;
    const char* Wbase = Abase + 16384;
    f16x8 af[2][2], wf[2][4];
#pragma unroll
    for (int kf = 0; kf < 2; ++kf) {
      const int ch = kf * 4 + g4;
#pragma unroll
      for (int m = 0; m < 2; ++m) {
        const int r = wr * 32 + m * 16 + col0;
        af[kf][m] = *(const f16x8*)(Abase + r * 128 + ((ch ^ (r & 7)) << 4));
      }
#pragma unroll
      for (int n = 0; n < 4; ++n) {
        const int r = CELL ? (n * 32 + wc * 16 + col0) : (wc * 64 + n * 16 + col0);
        wf[kf][n] = *(const f16x8*)(Wbase + r * 128 + ((ch ^ (r & 7)) << 4));
      }
    }
#pragma unroll
    for (int kf = 0; kf < 2; ++kf)
#pragma unroll
      for (int m = 0; m < 2; ++m)
#pragma unroll
        for (int n = 0; n < 4; ++n)
          acc[m][n] = __builtin_amdgcn_mfma_f32_16x16x32_f16(af[kf][m], wf[kf][n],
                                                             acc[m][n], 0, 0, 0);
    // no trailing barrier: compiler-inserted lgkmcnt before MFMAs + the
    // per-iter barrier above make buffer reuse at distance 4 race-free.
  }

  if (CELL) {
    const int j = nBase + wc * 16 + col0;
    const float bi = p.bias[j], bf_ = p.bias[j + 1024];
    const float bg = p.bias[j + 2048], bo = p.bias[j + 3072];
#pragma unroll
    for (int m = 0; m < 2; ++m) {
#pragma unroll
      for (int r = 0; r < 4; ++r) {
        const int b = bRow + wr * 32 + m * 16 + g4 * 4 + r;
        const float gi = acc[m][0][r] + bi;
        const float gf = acc[m][1][r] + bf_;
        const float gg = acc[m][2][r] + bg;
        const float go = acc[m][3][r] + bo;
        const size_t ci = (size_t)b * 1024 + j;
        const float cprev = p.czero ? 0.f : p.c0[ci];
        const float cn = sigm(gf) * cprev + sigm(gi) * tanhf(gg);
        p.c0[ci] = cn;
        const u16 hv = f2h(sigm(go) * tanhf(cn));
        p.d0[(size_t)b * p.ld0 + j] = hv;
        if (p.d1) p.d1[(size_t)b * p.ld1 + j] = hv;
      }
    }
  } else {
#pragma unroll
    for (int m = 0; m < 2; ++m)
#pragma unroll
      for (int n = 0; n < 4; ++n)
#pragma unroll
        for (int r = 0; r < 4; ++r) {
          const int b = bRow + wr * 32 + m * 16 + g4 * 4 + r;
          const int j = nBase + wc * 64 + n * 16 + col0;
          float v = acc[m][n][r] + p.bias[j];
          if (p.mode == M_TANH) {
            v = tanhf(v);
            const u16 hv = f2h(v);
            p.d0[(size_t)b * p.ld0 + j] = hv;
            if (p.d1) p.d1[(size_t)b * p.ld1 + j] = hv;
            if (p.c0) p.c0[(size_t)b * 1024 + j] = v;
            if (p.c1) p.c1[(size_t)b * 1024 + j] = v;
          } else if (p.mode == M_PLAIN) {
            p.d0[(size_t)b * p.ld0 + j] = f2h(v);
          } else {  // M_OUT
            if (j < 90) {
              p.d0[(size_t)b * p.ld0 + j] = f2h(v);
              p.fout[(size_t)b * 5760 + j] = sigm(v);
            }
          }
        }
  }
}

// ---- prologue kernels ----

// dst[r, 0:Ka]=a[r]; dst[r, Ka:Ka+gap]=0; dst[r, Ka+gap:+Kb]=b[r]; rows>=srcRows -> 0
__global__ void pack_w(u16* dst, const float* a, int Ka, const float* b, int Kb,
                       int gap, int Kp, int srcRows) {
  const int r = blockIdx.y;
  const int c = blockIdx.x * 256 + threadIdx.x;
  if (c >= Kp) return;
  float v = 0.f;
  if (r < srcRows) {
    if (c < Ka) v = a[(size_t)r * Ka + c];
    else if (c >= Ka + gap && c < Ka + gap + Kb) v = b[(size_t)r * Kb + (c - Ka - gap)];
  }
  dst[(size_t)r * Kp + c] = f2h(v);
}

struct BiasAll {
  float *bz, *bc0, *bc1, *bfc1, *bcfc, *bb0, *bb1, *bout;
  const float *fzb, *ci0, *ch0, *ci1, *ch1, *f1b, *cfb, *bi0, *bh0, *bi1, *bh1, *ob;
};
__global__ void pack_biases(BiasAll q) {
  int i = blockIdx.x * 256 + threadIdx.x;
  if (i < 1024) { q.bz[i] = q.fzb[i]; return; } i -= 1024;
  if (i < 4096) { q.bc0[i] = q.ci0[i] + q.ch0[i]; return; } i -= 4096;
  if (i < 4096) { q.bc1[i] = q.ci1[i] + q.ch1[i]; return; } i -= 4096;
  if (i < 512)  { q.bfc1[i] = q.f1b[i]; return; } i -= 512;
  if (i < 512)  { q.bcfc[i] = q.cfb[i]; return; } i -= 512;
  if (i < 4096) { q.bb0[i] = q.bi0[i] + q.bh0[i]; return; } i -= 4096;
  if (i < 4096) { q.bb1[i] = q.bi1[i] + q.bh1[i]; return; } i -= 4096;
  if (i < 128)  { q.bout[i] = (i < 90) ? q.ob[i] : 0.f; }
}

__global__ void conv_h(u16* dst, const float* src, long n) {
  for (long i = (long)blockIdx.x * blockDim.x + threadIdx.x; i < n;
       i += (long)gridDim.x * blockDim.x)
    dst[i] = f2h(src[i]);
}

// zero Xc0 cols 0:512 (cond_in0) and Xb0 cols 512:640 (p slot + 38-col pad).
// The pad cols (602:640) are never written again -> stay zero all call.
__global__ void zero_init(u32* xc0, u32* xb0) {
  const int i = blockIdx.x * 256 + threadIdx.x;
  if (i < 1024 * 256) {
    xc0[(i >> 8) * 768 + (i & 255)] = 0;
  } else {
    const int k = i - 1024 * 256;  // k < 1024*64
    xb0[(k >> 6) * 832 + 256 + (k & 63)] = 0;
  }
}

extern "C" void kernel_launch(void* const* d_in, const int* in_sizes, int n_in,
                              void* d_out, int out_size, void* d_ws, size_t ws_size,
                              hipStream_t stream) {
  const float* z      = (const float*)d_in[0];
  const float* fc_z_w = (const float*)d_in[2];
  const float* fc_z_b = (const float*)d_in[3];
  const float* cWih0  = (const float*)d_in[4];
  const float* cWhh0  = (const float*)d_in[5];
  const float* cbih0  = (const float*)d_in[6];
  const float* cbhh0  = (const float*)d_in[7];
  const float* cWih1  = (const float*)d_in[8];
  const float* cWhh1  = (const float*)d_in[9];
  const float* cbih1  = (const float*)d_in[10];
  const float* cbhh1  = (const float*)d_in[11];
  const float* fc1_w  = (const float*)d_in[12];
  const float* fc1_b  = (const float*)d_in[13];
  const float* cfc_w  = (const float*)d_in[14];
  const float* cfc_b  = (const float*)d_in[15];
  const float* bWih0  = (const float*)d_in[16];
  const float* bWhh0  = (const float*)d_in[17];
  const float* bbih0  = (const float*)d_in[18];
  const float* bbhh0  = (const float*)d_in[19];
  const float* bWih1  = (const float*)d_in[20];
  const float* bWhh1  = (const float*)d_in[21];
  const float* bbih1  = (const float*)d_in[22];
  const float* bbhh1  = (const float*)d_in[23];
  const float* out_w  = (const float*)d_in[24];
  const float* out_b  = (const float*)d_in[25];
  float* outp = (float*)d_out;

  char* w = (char*)d_ws;
  auto alloc = [&](size_t bytes) {
    char* p = w;
    w += (bytes + 255) & ~(size_t)255;
    return p;
  };
  u16* Wz   = (u16*)alloc((size_t)1024 * 512 * 2);
  u16* Wc0  = (u16*)alloc((size_t)4096 * 1536 * 2);
  u16* Wc1  = (u16*)alloc((size_t)4096 * 2048 * 2);
  u16* Wb0  = (u16*)alloc((size_t)4096 * 1664 * 2);
  u16* Wb1  = (u16*)alloc((size_t)4096 * 2048 * 2);
  u16* Wfc1 = (u16*)alloc((size_t)512 * 1024 * 2);
  u16* Wcfc = (u16*)alloc((size_t)512 * 512 * 2);
  u16* Wout = (u16*)alloc((size_t)128 * 1024 * 2);
  u16* zh   = (u16*)alloc((size_t)1024 * 512 * 2);
  u16* Xc0  = (u16*)alloc((size_t)1024 * 1536 * 2);  // [cond_in 512 | h1 1024]
  u16* Xc1  = (u16*)alloc((size_t)1024 * 2048 * 2);  // [h1 1024 | h2 1024]
  u16* Xb0  = (u16*)alloc((size_t)1024 * 1664 * 2);  // [emb 512|p 90|pad 38|bh1 1024]
  u16* Xb1  = (u16*)alloc((size_t)1024 * 2048 * 2);  // [bh1 1024 | bh2 1024]
  float* cc0  = (float*)alloc((size_t)1024 * 1024 * 4);
  float* cc1  = (float*)alloc((size_t)1024 * 1024 * 4);
  float* cbb0 = (float*)alloc((size_t)1024 * 1024 * 4);
  float* cbb1 = (float*)alloc((size_t)1024 * 1024 * 4);
  float* bz   = (float*)alloc(1024 * 4);
  float* bc0  = (float*)alloc(4096 * 4);
  float* bc1  = (float*)alloc(4096 * 4);
  float* bfc1 = (float*)alloc(512 * 4);
  float* bcfc = (float*)alloc(512 * 4);
  float* bb0  = (float*)alloc(4096 * 4);
  float* bb1  = (float*)alloc(4096 * 4);
  float* bout = (float*)alloc(128 * 4);

  const dim3 blk(256), blk5(512);
  const dim3 gcell(256);  // 1-D, XCD-swizzled inside kernel

  // --- prologue: pack weights (fp16, div-free 2D), biases, init state ---
  pack_w<<<dim3(2, 1024), blk, 0, stream>>>(Wz,   fc_z_w, 512,  nullptr, 0,    0,  512,  1024);
  pack_w<<<dim3(6, 4096), blk, 0, stream>>>(Wc0,  cWih0,  512,  cWhh0,   1024, 0,  1536, 4096);
  pack_w<<<dim3(8, 4096), blk, 0, stream>>>(Wc1,  cWih1,  1024, cWhh1,   1024, 0,  2048, 4096);
  pack_w<<<dim3(7, 4096), blk, 0, stream>>>(Wb0,  bWih0,  602,  bWhh0,   1024, 38, 1664, 4096);
  pack_w<<<dim3(8, 4096), blk, 0, stream>>>(Wb1,  bWih1,  1024, bWhh1,   1024, 0,  2048, 4096);
  pack_w<<<dim3(4, 512),  blk, 0, stream>>>(Wfc1, fc1_w,  1024, nullptr, 0,    0,  1024, 512);
  pack_w<<<dim3(2, 512),  blk, 0, stream>>>(Wcfc, cfc_w,  512,  nullptr, 0,    0,  512,  512);
  pack_w<<<dim3(4, 128),  blk, 0, stream>>>(Wout, out_w,  1024, nullptr, 0,    0,  1024, 90);
  {
    BiasAll q{bz, bc0, bc1, bfc1, bcfc, bb0, bb1, bout,
              fc_z_b, cbih0, cbhh0, cbih1, cbhh1, fc1_b, cfc_b,
              bbih0, bbhh0, bbih1, bbhh1, out_b};
    pack_biases<<<dim3(80), blk, 0, stream>>>(q);
  }
  conv_h<<<dim3(512), blk, 0, stream>>>(zh, z, 1024L * 512);
  zero_init<<<dim3(1280), blk, 0, stream>>>((u32*)Xc0, (u32*)Xb0);

  // s0 = tanh(z @ Wz^T + bz) -> h1, h2 (fp16) and c1, c2 (f32)
  {
    GemmP p;
    p.A = zh; p.lda = 512; p.W = Wz; p.ldw = 512; p.K = 512; p.bias = bz;
    p.mode = M_TANH; p.czero = 0;
    p.d0 = Xc0 + 512; p.ld0 = 1536; p.d1 = Xc1 + 1024; p.ld1 = 2048;
    p.c0 = cc0; p.c1 = cc1; p.fout = nullptr;
    gk<false><<<dim3(8, 8), blk5, 0, stream>>>(p);
  }

  for (int t = 0; t < 16; ++t) {
    {  // conductor layer 0
      GemmP p;
      p.A = Xc0; p.lda = 1536; p.W = Wc0; p.ldw = 1536; p.K = 1536; p.bias = bc0;
      p.mode = 0; p.czero = 0;
      p.d0 = Xc0 + 512; p.ld0 = 1536; p.d1 = Xc1; p.ld1 = 2048;
      p.c0 = cc0; p.c1 = nullptr; p.fout = nullptr;
      gk<true><<<gcell, blk5, 0, stream>>>(p);
    }
    {  // conductor layer 1
      GemmP p;
      p.A = Xc1; p.lda = 2048; p.W = Wc1; p.ldw = 2048; p.K = 2048; p.bias = bc1;
      p.mode = 0; p.czero = 0;
      p.d0 = Xc1 + 1024; p.ld0 = 2048; p.d1 = nullptr; p.ld1 = 0;
      p.c0 = cc1; p.c1 = nullptr; p.fout = nullptr;
      gk<true><<<gcell, blk5, 0, stream>>>(p);
    }
    {  // cond_out = h2 @ fc1^T + b -> Xc0 cols 0:512
      GemmP p;
      p.A = Xc1 + 1024; p.lda = 2048; p.W = Wfc1; p.ldw = 1024; p.K = 1024;
      p.bias = bfc1; p.mode = M_PLAIN; p.czero = 0;
      p.d0 = Xc0; p.ld0 = 1536; p.d1 = nullptr; p.ld1 = 0;
      p.c0 = nullptr; p.c1 = nullptr; p.fout = nullptr;
      gk<false><<<dim3(8, 4), blk5, 0, stream>>>(p);
    }
    {  // emb = tanh(cond_out @ cfc^T + b) -> Xb0 cols 0:512
      GemmP p;
      p.A = Xc0; p.lda = 1536; p.W = Wcfc; p.ldw = 512; p.K = 512;
      p.bias = bcfc; p.mode = M_TANH; p.czero = 0;
      p.d0 = Xb0; p.ld0 = 1664; p.d1 = nullptr; p.ld1 = 0;
      p.c0 = nullptr; p.c1 = nullptr; p.fout = nullptr;
      gk<false><<<dim3(8, 4), blk5, 0, stream>>>(p);
    }
    for (int s = 0; s < 4; ++s) {
      {  // bottom layer 0; s==0: bh1=0 & c=0 -> K=640, czero
        GemmP p;
        p.A = Xb0; p.lda = 1664; p.W = Wb0; p.ldw = 1664;
        p.K = (s == 0) ? 640 : 1664; p.bias = bb0;
        p.mode = 0; p.czero = (s == 0);
        p.d0 = Xb0 + 640; p.ld0 = 1664; p.d1 = Xb1; p.ld1 = 2048;
        p.c0 = cbb0; p.c1 = nullptr; p.fout = nullptr;
        gk<true><<<gcell, blk5, 0, stream>>>(p);
      }
      {  // bottom layer 1; s==0: bh2=0 & c=0 -> K=1024, czero
        GemmP p;
        p.A = Xb1; p.lda = 2048; p.W = Wb1; p.ldw = 2048;
        p.K = (s == 0) ? 1024 : 2048; p.bias = bb1;
        p.mode = 0; p.czero = (s == 0);
        p.d0 = Xb1 + 1024; p.ld0 = 2048; p.d1 = nullptr; p.ld1 = 0;
        p.c0 = cbb1; p.c1 = nullptr; p.fout = nullptr;
        gk<true><<<gcell, blk5, 0, stream>>>(p);
      }
      {  // p = bh2 @ out_w^T + b ; p (fp16) -> Xb0 p-slot, sigmoid -> d_out
        GemmP p;
        p.A = Xb1 + 1024; p.lda = 2048; p.W = Wout; p.ldw = 1024; p.K = 1024;
        p.bias = bout; p.mode = M_OUT; p.czero = 0;
        p.d0 = Xb0 + 512; p.ld0 = 1664; p.d1 = nullptr; p.ld1 = 0;
        p.c0 = nullptr; p.c1 = nullptr;
        p.fout = outp + (size_t)(t * 4 + s) * 90;
        gk<false><<<dim3(8, 1), blk5, 0, stream>>>(p);
      }
    }
  }
}